// Round 7
// baseline (30.242 us; speedup 1.0000x reference)
//
#include <hip/hip_runtime.h>
#include <stdint.h>

#define TILE_LEN 16
#define KMAX 64
#define IMGW 512
#define IMGH 512
#define TXN 32
#define TYN 32
#define TPB 4                    // tiles per block (along x, same tile-row)
#define NBLK ((TXN * TYN) / TPB) // 256 blocks
#define BT 1024                  // threads per block
#define NWAVE (BT / 64)          // 16 waves
#define WCAP 96                  // per-wave survivor cap (mean ~9, huge margin)
#define SURVCAP 512              // dense survivor cap (mean ~147)
#define CCAP 256                 // per-tile candidate cap (mean ~46)

// ---------------------------------------------------------------------------
// Single fused kernel. Block b owns tiles (txb..txb+3, ty), ty = b & 31.
//  1a) conservative sqrt-free prefilter (r <= 3*sqrt(trace) for PSD cov;
//      2% slack vs rounding). Survivors compacted into PER-WAVE private LDS
//      segments: position = wcnt + popc(ballot & below-lane-mask), wcnt is
//      lane-uniform -- NO cross-wave atomics, no shfl in the hot loop.
//      Scan unrolled x2 with both loads issued up front.
//  1a') 16-entry prefix + wave-parallel merge into dense survivor list
//      (order nondeterministic -- made irrelevant by the unique-key sort).
//  1b) exact _rn radius chain + exact y/x overlap tests on survivors only.
//      Byte-identical selection arithmetic to the passing kernels.
//  2)  per-tile stable depth sort: rank sort over unique 64-bit keys
//      (depth_bits << 32) | idx  (depth >= 0 -> bits order-isomorphic).
//  3)  gather first min(M,64) params (precompute 1/det), blend, store.
// ---------------------------------------------------------------------------
__global__ __launch_bounds__(BT) void fused_splat(
    const float* __restrict__ pos2d, const float* __restrict__ cov2d,
    const float* __restrict__ opac,  const float* __restrict__ color,
    const float* __restrict__ depth, float* __restrict__ out, int N)
{
    __shared__ int      s_seg[NWAVE * WCAP];
    __shared__ int      s_wsc[NWAVE];
    __shared__ int      s_wbase[NWAVE + 1];
    __shared__ int      s_surv[SURVCAP];
    __shared__ int      s_cnt[TPB];
    __shared__ int      s_cand[TPB][CCAP];
    __shared__ uint64_t s_keys[TPB][CCAP];
    __shared__ int      s_sel[TPB][KMAX];
    __shared__ float4   pA[TPB][KMAX], pB[TPB][KMAX], pC[TPB][KMAX];

    const int t    = threadIdx.x;
    const int lane = t & 63;
    const int w    = t >> 6;
    const int ty   = blockIdx.x & (TYN - 1);
    const int txb  = (blockIdx.x >> 5) * TPB;
    const float Tf  = (float)(ty * TILE_LEN);
    const float Lf0 = (float)(txb * TILE_LEN);
    const float Yc  = Tf + 8.0f;     // row band center
    const float Xc  = Lf0 + 32.0f;   // 4-tile band center

    if (t < TPB) s_cnt[t] = 0;
    __syncthreads();

    const float2* __restrict__ posv = (const float2*)pos2d;
    const float4* __restrict__ covv = (const float4*)cov2d;
    const unsigned long long below = (1ull << lane) - 1ull;

    // ---- Phase 1a: prefilter scan, per-wave private compaction, unroll x2
    int wcnt = 0;
    for (int base = 0; base < N; base += 2 * BT) {
        const int i0 = base + t;
        const int i1 = base + BT + t;
        bool sv0 = false, sv1 = false;
        if (i0 < N) {
            const float2 p  = posv[i0];
            const float4 cv = covv[i0];
            const float rb2 = 9.2f * (cv.x + cv.w);
            const float sy = fabsf(p.y - Yc) - 8.0f;
            const float sx = fabsf(p.x - Xc) - 32.0f;
            sv0 = !(((sy > 0.0f) && (sy * sy > rb2)) ||
                    ((sx > 0.0f) && (sx * sx > rb2)));
        }
        if (i1 < N) {
            const float2 p  = posv[i1];
            const float4 cv = covv[i1];
            const float rb2 = 9.2f * (cv.x + cv.w);
            const float sy = fabsf(p.y - Yc) - 8.0f;
            const float sx = fabsf(p.x - Xc) - 32.0f;
            sv1 = !(((sy > 0.0f) && (sy * sy > rb2)) ||
                    ((sx > 0.0f) && (sx * sx > rb2)));
        }
        const unsigned long long m0 = __ballot(sv0);
        if (sv0) {
            const int pos = wcnt + __popcll(m0 & below);
            if (pos < WCAP) s_seg[w * WCAP + pos] = i0;
        }
        wcnt += __popcll(m0);
        const unsigned long long m1 = __ballot(sv1);
        if (sv1) {
            const int pos = wcnt + __popcll(m1 & below);
            if (pos < WCAP) s_seg[w * WCAP + pos] = i1;
        }
        wcnt += __popcll(m1);
    }
    if (lane == 0) s_wsc[w] = min(wcnt, WCAP);
    __syncthreads();

    // ---- Phase 1a': prefix over wave counts + wave-parallel dense merge
    if (t == 0) {
        int s = 0;
        for (int v = 0; v < NWAVE; ++v) { s_wbase[v] = s; s += s_wsc[v]; }
        s_wbase[NWAVE] = s;
    }
    __syncthreads();
    const int S = min(s_wbase[NWAVE], SURVCAP);
    {
        const int cnt = s_wsc[w];
        const int b0 = s_wbase[w];
        for (int k = lane; k < cnt; k += 64) {
            const int dst = b0 + k;
            if (dst < SURVCAP) s_surv[dst] = s_seg[w * WCAP + k];
        }
    }
    __syncthreads();

    // ---- Phase 1b: exact selection tests on survivors (dense)
    for (int k = t; k < S; k += BT) {
        const int i = s_surv[k];
        const float2 p  = posv[i];
        const float4 cv = covv[i];
        const float a = cv.x, b = cv.y, c = cv.w;

        // radius chain with _rn intrinsics: forbids fma contraction
        // (selection-critical, feeds exact bbox-overlap compares)
        const float trace = __fadd_rn(a, c);
        const float det   = __fsub_rn(__fmul_rn(a, c), __fmul_rn(b, b));
        float arg = __fsub_rn(__fmul_rn(trace, trace), __fmul_rn(4.0f, det));
        arg = fmaxf(arg, 0.0f);
        const float t1 = __fmul_rn(0.5f, trace);
        const float t2 = __fmul_rn(0.5f, sqrtf(arg));
        const float lam = fmaxf(__fsub_rn(t1, t2), __fadd_rn(t1, t2));
        const float r = __fmul_rn(3.0f, sqrtf(lam));

        const float yp = __fadd_rn(p.y, r);
        const float ym = __fsub_rn(p.y, r);
        if ((yp > Tf) && (ym < Tf + (float)TILE_LEN)) {
            const float xp = __fadd_rn(p.x, r);
            const float xm = __fsub_rn(p.x, r);
#pragma unroll
            for (int g = 0; g < TPB; ++g) {
                const float Lf = Lf0 + (float)(g * TILE_LEN);
                if ((xp > Lf) && (xm < Lf + (float)TILE_LEN)) {
                    const int pos = atomicAdd(&s_cnt[g], 1);   // LDS atomic, ~150 total
                    if (pos < CCAP) s_cand[g][pos] = i;
                }
            }
        }
    }
    __syncthreads();

    // ---- Phase 2: per-tile stable depth sort (rank sort, unique keys)
    const int g8 = t >> 8;    // tile group 0..3 (256 threads each)
    const int m  = t & 255;
    const int M  = min(s_cnt[g8], CCAP);

    uint64_t mykey = 0;
    int myidx = -1;
    if (m < M) {
        myidx = s_cand[g8][m];
        mykey = ((uint64_t)__float_as_uint(depth[myidx]) << 32) | (uint32_t)myidx;
        s_keys[g8][m] = mykey;
    }
    __syncthreads();

    if (m < M) {
        int rank = 0;
        for (int j = 0; j < M; ++j)
            rank += (s_keys[g8][j] < mykey) ? 1 : 0;
        if (rank < KMAX) s_sel[g8][rank] = myidx;   // unique ranks
    }
    __syncthreads();

    // ---- Phase 3a: gather selected gaussians' params into LDS
    if (t < TPB * KMAX) {
        const int g = t >> 6, k = t & 63;
        const int K = min(min(s_cnt[g], CCAP), KMAX);
        if (k < K) {
            const int idx = s_sel[g][k];
            const float2 p  = posv[idx];
            const float4 cv = covv[idx];
            const float det = __fsub_rn(__fmul_rn(cv.x, cv.w), __fmul_rn(cv.y, cv.y));
            pA[g][k] = make_float4(p.x, p.y, 0.0f, opac[idx]);
            pB[g][k] = make_float4(cv.x, cv.y, cv.w, 1.0f / det);
            pC[g][k] = make_float4(color[3 * idx], color[3 * idx + 1],
                                   color[3 * idx + 2], 0.0f);
        }
    }
    __syncthreads();

    // ---- Phase 3b: per-pixel front-to-back blend (all 1024 threads)
    const int pix = t & 255;
    const int pi = pix >> 4;       // x offset in tile
    const int pj = pix & 15;       // y offset in tile
    const int K = min(M, KMAX);
    const float x = Lf0 + (float)(g8 * TILE_LEN + pi);
    const float y = Tf + (float)pj;

    float Tacc = 1.0f, cr = 0.0f, cg = 0.0f, cb = 0.0f;
    for (int k = 0; k < K; ++k) {
        const float4 A  = pA[g8][k];
        const float4 B  = pB[g8][k];
        const float4 Cc = pC[g8][k];
        const float dx = x - A.x;
        const float dy = y - A.y;
        const float quad = (B.z * dx * dx - 2.0f * B.y * dx * dy + B.x * dy * dy) * B.w;
        const float prob = __expf(-0.5f * quad);
        const float alpha = fminf(fmaxf(A.w * prob, 0.01f), 0.99f);
        const float wgt = alpha * Tacc;
        cr = fmaf(wgt, Cc.x, cr);
        cg = fmaf(wgt, Cc.y, cg);
        cb = fmaf(wgt, Cc.z, cb);
        Tacc *= (1.0f - alpha);
    }

    const int X = (txb + g8) * TILE_LEN + pi;
    const int Y = ty * TILE_LEN + pj;
    float* o = out + ((size_t)X * IMGW + (size_t)Y) * 3;
    o[0] = cr;
    o[1] = cg;
    o[2] = cb;
}

// ---------------------------------------------------------------------------
extern "C" void kernel_launch(void* const* d_in, const int* in_sizes, int n_in,
                              void* d_out, int out_size, void* d_ws, size_t ws_size,
                              hipStream_t stream)
{
    const float* pos2d = (const float*)d_in[0];
    const float* cov2d = (const float*)d_in[1];
    const float* opac  = (const float*)d_in[2];
    const float* color = (const float*)d_in[3];
    const float* depth = (const float*)d_in[4];
    float* out = (float*)d_out;

    const int N = in_sizes[2];  // opacity count == N_GAUSS

    fused_splat<<<NBLK, BT, 0, stream>>>(pos2d, cov2d, opac, color, depth, out, N);
}